// Round 8
// baseline (158.869 us; speedup 1.0000x reference)
//
#include <hip/hip_runtime.h>
#include <hip/hip_bf16.h>

using bf16x8 = __attribute__((ext_vector_type(8))) short;
using f32x4  = __attribute__((ext_vector_type(4))) float;

constexpr int CH  = 64;
constexpr int HW  = 11;
constexpr int NP  = 121;
constexpr int PPW = 14;          // padded pos-grid row width
constexpr int NROW = 182;        // padded rows (13*14)
constexpr int ICL = 72;          // LDS ic stride in pool staging (bank-safe)
constexpr int IMG_S = NROW * 64; // ushorts per sample image (row stride 64 = 128B)
constexpr int NO  = 7168;        // padded o rows (112 oc * 64 ic)
constexpr float EPS = 1e-5f;

__device__ __forceinline__ f32x4 MFMA(bf16x8 a, bf16x8 b, f32x4 c) {
    return __builtin_amdgcn_mfma_f32_16x16x32_bf16(a, b, c, 0, 0, 0);
}

// ---- prep: bake BN-scaled gw into gen-MFMA A-fragment order + beta ----
__global__ __launch_bounds__(256) void prep_kernel(
    const float* __restrict__ gw, const float* __restrict__ gb,
    const float* __restrict__ bng, const float* __restrict__ bnb,
    const float* __restrict__ bnm, const float* __restrict__ bnv,
    unsigned short* __restrict__ Aprep, float* __restrict__ Beta)
{
    int o = blockIdx.x * 256 + threadIdx.x;
    if (o >= NO) return;
    float inv = 0.f, beta = 0.f;
    if (o < 6400) {
        inv  = bng[o] * rsqrtf(bnv[o] + EPS);
        beta = (gb[o] - bnm[o]) * inv + bnb[o];
    }
    Beta[o] = beta;
    int tile = o >> 4, lrow = o & 15;
    #pragma unroll
    for (int jg = 0; jg < 4; ++jg) {
        bf16x8 f;
        #pragma unroll
        for (int r = 0; r < 8; ++r) {
            int k = jg * 8 + r;
            float v = (o < 6400 && k < 18) ? gw[(size_t)o * 18 + k] * inv : 0.f;
            __hip_bfloat16 h = __float2bfloat16(v);
            f[r] = *(short*)&h;
        }
        ((bf16x8*)Aprep)[tile * 64 + jg * 16 + lrow] = f;
    }
}

// ---- pool: coalesced load -> LDS(72-stride) -> pooled stats + linear img dump ----
__global__ __launch_bounds__(256) void pool_kernel(
    const float* __restrict__ x_in,
    unsigned short* __restrict__ img,   // [1024][IMG_S], row stride 64 ush = 128B
    unsigned short* __restrict__ Bg)    // [1024][512]
{
    __shared__ alignas(16) unsigned short xsT[NROW * ICL];  // 26208 B
    __shared__ float xh[2][128];
    __shared__ float xhp[2][2][128];

    const int phys = blockIdx.x;
    const int b = (phys & 7) * 128 + (phys >> 3);   // XCD-chunked
    const int t = threadIdx.x, lane = t & 63, wave = t >> 6;
    const float* xb = x_in + (size_t)b * (CH * NP);
    unsigned short* ib = img + (size_t)b * IMG_S;

    for (int i = t; i < NROW * ICL / 2; i += 256) ((unsigned int*)xsT)[i] = 0u;
    __syncthreads();

    // coalesced fp32 loads (lane->pos), bf16 scatter into LDS (2-way banks max)
    {
        int p = (wave & 1) * 64 + lane, ich = wave >> 1;
        if (p < NP) {
            int pp = (p / HW + 1) * PPW + (p % HW + 1);
            float s = 0.f, m = -INFINITY;
            const float* xc = xb + (ich * 32) * NP + p;
            #pragma unroll 8
            for (int q = 0; q < 32; ++q) {
                float v = xc[q * NP];
                s += v; m = fmaxf(m, v);
                __hip_bfloat16 h = __float2bfloat16(v);
                xsT[pp * ICL + ich * 32 + q] = *(unsigned short*)&h;
            }
            xhp[ich][0][p] = s;
            xhp[ich][1][p] = m;
        }
    }
    __syncthreads();
    if (t < NP) {
        xh[0][t] = (xhp[0][0][t] + xhp[1][0][t]) * (1.f / 64.f);
        xh[1][t] = fmaxf(xhp[0][1][t], xhp[1][1][t]);
    }
    __syncthreads();

    // Bg[tap(16)][k(32)] zero-padded gen-B matrix
    for (int i = t; i < 512; i += 256) {
        int tap = i >> 5, k = i & 31;
        float val = 0.f;
        if (tap < 9 && k < 18) {
            int ci = k / 9, o9 = k - ci * 9, u = o9 / 3, v = o9 - u * 3;
            int kh = tap / 3, kw = tap - kh * 3;
            val = xh[ci][(4 * kh + u) * HW + (4 * kw + v)];
        }
        __hip_bfloat16 h = __float2bfloat16(val);
        Bg[b * 512 + i] = *(unsigned short*)&h;
    }

    // dump LDS(72-stride) -> img(64-stride): 16B reads (conflict-free), 16B stores
    for (int i = t; i < NROW * 8; i += 256) {
        int row = i >> 3, cb = i & 7;
        *(int4*)(ib + row * 64 + cb * 8) =
            *(const int4*)(xsT + row * ICL + cb * 8);
    }
}

// ---- main: block = (sample, 16-oc chunk); strip-only LDS; B from L2 ----
__global__ __launch_bounds__(256, 6) void hsi_main(
    const unsigned short* __restrict__ img,
    const unsigned short* __restrict__ Bg,
    const unsigned short* __restrict__ Aprep,
    const float* __restrict__ Beta,
    float* __restrict__ out)
{
    // strip: W for 16 ocs in main-A-fragment slot order:
    //   slot(ks=(tap*2+h), l) holds A[row=l&15][k=(l>>4)*8+r], stored at l^tap
    __shared__ alignas(16) unsigned short strip[18 * 64 * 8];  // 18432 B

    const int phys = blockIdx.x;
    const int L = (phys & 7) * 896 + (phys >> 3);   // XCD-chunked bijection
    const int b = L / 7, c = L - b * 7;             // sample, oc-chunk
    const int t = threadIdx.x;
    const int lane = t & 63;
    const int wave = t >> 6;
    const int lrow = lane & 15, jg = lane >> 4;

    // gen-B fragment (16B/lane, row-aligned 64B lines)
    const bf16x8 Bgen = *(const bf16x8*)(Bg + b * 512 + lrow * 32 + jg * 8);

    // ---- gen: 16 MFMAs/wave -> pack bf16 -> fragment-slot strip ----
    #pragma unroll 4
    for (int it = 0; it < 16; ++it) {
        int tl = wave * 16 + it;          // chunk-local gen tile (0..63)
        int tG = c * 64 + tl;             // global gen tile (<448)
        bf16x8 A = *(const bf16x8*)(Aprep + ((size_t)tG * 64 + lane) * 8);
        f32x4 acc{};
        acc = MFMA(A, Bgen, acc);
        float4 bet = *(const float4*)(Beta + tG * 16 + jg * 4);
        if (lrow < 9) {                   // C col = tap = lrow; rows = 4 ics
            float v0 = fmaxf(acc[0] + bet.x, 0.f);
            float v1 = fmaxf(acc[1] + bet.y, 0.f);
            float v2 = fmaxf(acc[2] + bet.z, 0.f);
            float v3 = fmaxf(acc[3] + bet.w, 0.f);
            __hip_bfloat16 h0 = __float2bfloat16(v0), h1 = __float2bfloat16(v1);
            __hip_bfloat16 h2 = __float2bfloat16(v2), h3 = __float2bfloat16(v3);
            unsigned int lo = (unsigned int)*(unsigned short*)&h0 |
                              ((unsigned int)*(unsigned short*)&h1 << 16);
            unsigned int hi = (unsigned int)*(unsigned short*)&h2 |
                              ((unsigned int)*(unsigned short*)&h3 << 16);
            // value = W[oc_l][ic = icb*16 + jg*4 + q][tap=lrow]
            int oc_l = tl >> 2, icb = tl & 3;
            int h   = icb >> 1;                    // k-half
            int jgr = (icb & 1) * 2 + (jg >> 1);   // reader k-group
            int slot = (jgr * 16 + oc_l) ^ lrow;   // XOR keeps banks spread
            uint2 pk; pk.x = lo; pk.y = hi;
            *(uint2*)(strip + ((lrow * 2 + h) * 64 + slot) * 8 + (jg & 1) * 4) = pk;
        }
    }
    __syncthreads();   // the only barrier

    // ---- main GEMM: wave owns 2 N-tiles; A slot-read (conflict-free), B from L2 ----
    const unsigned short* imgb = img + (size_t)b * IMG_S;
    int p0 = wave * 32 + lrow;
    int p1 = p0 + 16;
    int pc0 = p0 > 120 ? 120 : p0;
    int pc1 = p1 > 120 ? 120 : p1;
    int base0 = (pc0 / HW) * PPW + (pc0 % HW);
    int base1 = (pc1 / HW) * PPW + (pc1 % HW);

    f32x4 acc0{}, acc1{};
    #pragma unroll
    for (int tap = 0; tap < 9; ++tap) {
        int off = (tap / 3) * PPW + (tap % 3);
        int r0 = (base0 + off) * 64;
        int r1 = (base1 + off) * 64;
        #pragma unroll
        for (int h = 0; h < 2; ++h) {
            bf16x8 Af = *(const bf16x8*)&strip[((tap * 2 + h) * 64 + (lane ^ tap)) * 8];
            bf16x8 B0 = *(const bf16x8*)&imgb[r0 + h * 32 + jg * 8];
            bf16x8 B1 = *(const bf16x8*)&imgb[r1 + h * 32 + jg * 8];
            acc0 = MFMA(Af, B0, acc0);
            acc1 = MFMA(Af, B1, acc1);
        }
    }

    float* ob = out + (size_t)b * 100 * NP;
    #pragma unroll
    for (int ri = 0; ri < 4; ++ri) {
        int oc = c * 16 + jg * 4 + ri;
        if (oc < 100) {
            if (p0 < NP) ob[oc * NP + p0] = acc0[ri];
            if (p1 < NP) ob[oc * NP + p1] = acc1[ri];
        }
    }
}

extern "C" void kernel_launch(void* const* d_in, const int* in_sizes, int n_in,
                              void* d_out, int out_size, void* d_ws, size_t ws_size,
                              hipStream_t stream) {
    const float* x  = (const float*)d_in[0];
    const float* gw = (const float*)d_in[1];
    const float* gb = (const float*)d_in[2];
    const float* bg = (const float*)d_in[3];
    const float* bb = (const float*)d_in[4];
    const float* bm = (const float*)d_in[5];
    const float* bv = (const float*)d_in[6];
    float* out = (float*)d_out;

    // ws: Aprep 458752 | Beta 28672 | Bg 1048576 | img 1024*23296  (~25 MiB)
    unsigned short* Aprep = (unsigned short*)d_ws;
    float* Beta = (float*)((char*)d_ws + 458752);
    unsigned short* Bgm = (unsigned short*)((char*)d_ws + 487424);
    unsigned short* img = (unsigned short*)((char*)d_ws + 1536000);

    prep_kernel<<<NO / 256, 256, 0, stream>>>(gw, gb, bg, bb, bm, bv, Aprep, Beta);
    pool_kernel<<<1024, 256, 0, stream>>>(x, img, Bgm);
    hsi_main<<<1024 * 7, 256, 0, stream>>>(img, Bgm, Aprep, Beta, out);
}

// Round 9
// 108.494 us; speedup vs baseline: 1.4643x; 1.4643x over previous
//
#include <hip/hip_runtime.h>
#include <hip/hip_bf16.h>

using bf16x8 = __attribute__((ext_vector_type(8))) short;
using f32x4  = __attribute__((ext_vector_type(4))) float;

constexpr int CH  = 64;
constexpr int HW  = 11;
constexpr int NP  = 121;
constexpr int PPW = 14;            // padded pos-grid row width
constexpr int NROW = 182;          // padded rows (13*14)
constexpr int ICL = 72;            // ic stride (ush) in img/LDS (bank-safe)
constexpr int IMG_USH = NROW * ICL;        // 13104 ush = 26208 B per sample
constexpr int IMG_I4  = IMG_USH / 8;       // 1638 int4
constexpr int NO  = 7168;          // padded o rows (112 oc * 64 ic)
constexpr float EPS = 1e-5f;

__device__ __forceinline__ f32x4 MFMA(bf16x8 a, bf16x8 b, f32x4 c) {
    return __builtin_amdgcn_mfma_f32_16x16x32_bf16(a, b, c, 0, 0, 0);
}

// ---- prep: bake BN-scaled gw into gen-MFMA A-fragment order + beta ----
__global__ __launch_bounds__(256) void prep_kernel(
    const float* __restrict__ gw, const float* __restrict__ gb,
    const float* __restrict__ bng, const float* __restrict__ bnb,
    const float* __restrict__ bnm, const float* __restrict__ bnv,
    unsigned short* __restrict__ Aprep, float* __restrict__ Beta)
{
    int o = blockIdx.x * 256 + threadIdx.x;
    if (o >= NO) return;
    float inv = 0.f, beta = 0.f;
    if (o < 6400) {
        inv  = bng[o] * rsqrtf(bnv[o] + EPS);
        beta = (gb[o] - bnm[o]) * inv + bnb[o];
    }
    Beta[o] = beta;
    int tile = o >> 4, lrow = o & 15;
    #pragma unroll
    for (int jg = 0; jg < 4; ++jg) {
        bf16x8 f;
        #pragma unroll
        for (int r = 0; r < 8; ++r) {
            int k = jg * 8 + r;
            float v = (o < 6400 && k < 18) ? gw[(size_t)o * 18 + k] * inv : 0.f;
            __hip_bfloat16 h = __float2bfloat16(v);
            f[r] = *(short*)&h;
        }
        ((bf16x8*)Aprep)[tile * 64 + jg * 16 + lrow] = f;
    }
}

// ---- pool: coalesced load -> LDS(72-stride) -> stats + linear img dump ----
__global__ __launch_bounds__(256) void pool_kernel(
    const float* __restrict__ x_in,
    unsigned short* __restrict__ img,   // [1024][IMG_USH], 72-ush rows
    unsigned short* __restrict__ Bg)    // [1024][512]
{
    __shared__ alignas(16) unsigned short xsT[IMG_USH];  // 26208 B
    __shared__ float xh[2][128];
    __shared__ float xhp[2][2][128];

    const int phys = blockIdx.x;
    const int b = (phys & 7) * 128 + (phys >> 3);   // XCD-chunked
    const int t = threadIdx.x, lane = t & 63, wave = t >> 6;
    const float* xb = x_in + (size_t)b * (CH * NP);
    unsigned short* ib = img + (size_t)b * IMG_USH;

    for (int i = t; i < IMG_USH / 2; i += 256) ((unsigned int*)xsT)[i] = 0u;
    __syncthreads();

    {   // coalesced fp32 loads (lane->pos), bf16 scatter (2-way banks max)
        int p = (wave & 1) * 64 + lane, ich = wave >> 1;
        if (p < NP) {
            int pp = (p / HW + 1) * PPW + (p % HW + 1);
            float s = 0.f, m = -INFINITY;
            const float* xc = xb + (ich * 32) * NP + p;
            #pragma unroll 8
            for (int q = 0; q < 32; ++q) {
                float v = xc[q * NP];
                s += v; m = fmaxf(m, v);
                __hip_bfloat16 h = __float2bfloat16(v);
                xsT[pp * ICL + ich * 32 + q] = *(unsigned short*)&h;
            }
            xhp[ich][0][p] = s;
            xhp[ich][1][p] = m;
        }
    }
    __syncthreads();
    if (t < NP) {
        xh[0][t] = (xhp[0][0][t] + xhp[1][0][t]) * (1.f / 64.f);
        xh[1][t] = fmaxf(xhp[0][1][t], xhp[1][1][t]);
    }
    __syncthreads();

    // Bg[tap(16)][k(32)] zero-padded gen-B matrix
    for (int i = t; i < 512; i += 256) {
        int tap = i >> 5, k = i & 31;
        float val = 0.f;
        if (tap < 9 && k < 18) {
            int ci = k / 9, o9 = k - ci * 9, u = o9 / 3, v = o9 - u * 3;
            int kh = tap / 3, kw = tap - kh * 3;
            val = xh[ci][(4 * kh + u) * HW + (4 * kw + v)];
        }
        __hip_bfloat16 h = __float2bfloat16(val);
        Bg[b * 512 + i] = *(unsigned short*)&h;
    }

    // linear dump LDS -> img (16B reads conflict-free, 16B coalesced stores)
    for (int i = t; i < IMG_I4; i += 256)
        ((int4*)ib)[i] = ((const int4*)xsT)[i];
}

// ---- main: 512 thr = (sample, 2x14-oc chunks); img+strips LDS; 1 barrier ----
__global__ __launch_bounds__(512, 4) void hsi_main(
    const unsigned short* __restrict__ img,
    const unsigned short* __restrict__ Bg,
    const unsigned short* __restrict__ Aprep,
    const float* __restrict__ Beta,
    float* __restrict__ out)
{
    __shared__ alignas(16) unsigned short xs[IMG_USH];        // 26208 B
    __shared__ alignas(16) unsigned short strip[2][18 * 64 * 8]; // 36864 B
    // total 63072 B -> 2 blocks/CU (16 waves)

    const int phys = blockIdx.x;
    const int L = (phys & 7) * 512 + (phys >> 3);   // XCD-chunked bijection
    const int b = L >> 2, d = L & 3;                // sample, chunk-pair
    const int t = threadIdx.x;
    const int lane = t & 63, wave = t >> 6;
    const int lrow = lane & 15, jg = lane >> 4;
    const int cl = wave >> 2;                       // strip/chunk select (0/1)
    const int chunk = d * 2 + cl;                   // 14-oc chunk (0..7)

    // 1) issue img loads early (hide under gen)
    const int4* ibv = (const int4*)(img + (size_t)b * IMG_USH);
    int4 st[4];
    #pragma unroll
    for (int k = 0; k < 4; ++k) {
        int idx = t + k * 512;
        if (idx < IMG_I4) st[k] = ibv[idx];
    }

    // 2) gen-B fragment
    const bf16x8 Bgen = *(const bf16x8*)(Bg + b * 512 + lrow * 32 + jg * 8);

    // 3) gen: 14 MFMAs/wave -> fragment-slot strip (R8-validated layout)
    unsigned short* sp = strip[cl];
    #pragma unroll 2
    for (int it = 0; it < 14; ++it) {
        int tl = (wave & 3) * 14 + it;    // chunk-local gen tile (0..55)
        int tG = chunk * 56 + tl;         // global gen tile (<448)
        bf16x8 A = *(const bf16x8*)(Aprep + ((size_t)tG * 64 + lane) * 8);
        f32x4 acc{};
        acc = MFMA(A, Bgen, acc);
        float4 bet = *(const float4*)(Beta + tG * 16 + jg * 4);
        if (lrow < 9) {                   // C col = tap = lrow; rows = 4 ics
            float v0 = fmaxf(acc[0] + bet.x, 0.f);
            float v1 = fmaxf(acc[1] + bet.y, 0.f);
            float v2 = fmaxf(acc[2] + bet.z, 0.f);
            float v3 = fmaxf(acc[3] + bet.w, 0.f);
            __hip_bfloat16 h0 = __float2bfloat16(v0), h1 = __float2bfloat16(v1);
            __hip_bfloat16 h2 = __float2bfloat16(v2), h3 = __float2bfloat16(v3);
            unsigned int lo = (unsigned int)*(unsigned short*)&h0 |
                              ((unsigned int)*(unsigned short*)&h1 << 16);
            unsigned int hi = (unsigned int)*(unsigned short*)&h2 |
                              ((unsigned int)*(unsigned short*)&h3 << 16);
            // value = W[oc_l][ic = icb*16 + jg*4 + q][tap=lrow]
            int oc_l = tl >> 2, icb = tl & 3;
            int h   = icb >> 1;                    // k-half
            int jgr = (icb & 1) * 2 + (jg >> 1);   // reader k-group
            int slot = (jgr * 16 + oc_l) ^ lrow;
            uint2 pk; pk.x = lo; pk.y = hi;
            *(uint2*)(sp + ((lrow * 2 + h) * 64 + slot) * 8 + (jg & 1) * 4) = pk;
        }
    }

    // 4) write staged img into LDS (linear, conflict-free)
    #pragma unroll
    for (int k = 0; k < 4; ++k) {
        int idx = t + k * 512;
        if (idx < IMG_I4) ((int4*)xs)[idx] = st[k];
    }

    __syncthreads();   // the only barrier

    // 5) main GEMM: wave = (chunk cl, N-tile pair wave&3); A slot-read, B from LDS
    int p0 = (wave & 3) * 32 + lrow;
    int p1 = p0 + 16;
    int pc0 = p0 > 120 ? 120 : p0;
    int pc1 = p1 > 120 ? 120 : p1;
    int base0 = (pc0 / HW) * PPW + (pc0 % HW);
    int base1 = (pc1 / HW) * PPW + (pc1 % HW);

    f32x4 acc0{}, acc1{};
    #pragma unroll
    for (int tap = 0; tap < 9; ++tap) {
        int off = (tap / 3) * PPW + (tap % 3);
        int r0 = (base0 + off) * ICL;
        int r1 = (base1 + off) * ICL;
        #pragma unroll
        for (int h = 0; h < 2; ++h) {
            bf16x8 Af = *(const bf16x8*)&sp[((tap * 2 + h) * 64 + (lane ^ tap)) * 8];
            bf16x8 B0 = *(const bf16x8*)&xs[r0 + h * 32 + jg * 8];
            bf16x8 B1 = *(const bf16x8*)&xs[r1 + h * 32 + jg * 8];
            acc0 = MFMA(Af, B0, acc0);
            acc1 = MFMA(Af, B1, acc1);
        }
    }

    float* ob = out + (size_t)b * 100 * NP;
    #pragma unroll
    for (int ri = 0; ri < 4; ++ri) {
        int row = jg * 4 + ri;            // oc-local; rows 14,15 = next chunk
        int oc = chunk * 14 + row;
        if (row < 14 && oc < 100) {
            if (p0 < NP) ob[oc * NP + p0] = acc0[ri];
            if (p1 < NP) ob[oc * NP + p1] = acc1[ri];
        }
    }
}

extern "C" void kernel_launch(void* const* d_in, const int* in_sizes, int n_in,
                              void* d_out, int out_size, void* d_ws, size_t ws_size,
                              hipStream_t stream) {
    const float* x  = (const float*)d_in[0];
    const float* gw = (const float*)d_in[1];
    const float* gb = (const float*)d_in[2];
    const float* bg = (const float*)d_in[3];
    const float* bb = (const float*)d_in[4];
    const float* bm = (const float*)d_in[5];
    const float* bv = (const float*)d_in[6];
    float* out = (float*)d_out;

    // ws: Aprep 458752 | Beta 28672 | Bg 1048576 | img 1024*26208  (~28.2 MiB)
    unsigned short* Aprep = (unsigned short*)d_ws;
    float* Beta = (float*)((char*)d_ws + 458752);
    unsigned short* Bgm = (unsigned short*)((char*)d_ws + 487424);
    unsigned short* img = (unsigned short*)((char*)d_ws + 1536000);

    prep_kernel<<<NO / 256, 256, 0, stream>>>(gw, gb, bg, bb, bm, bv, Aprep, Beta);
    pool_kernel<<<1024, 256, 0, stream>>>(x, img, Bgm);
    hsi_main<<<1024 * 4, 512, 0, stream>>>(img, Bgm, Aprep, Beta, out);
}

// Round 10
// 90.133 us; speedup vs baseline: 1.7626x; 1.2037x over previous
//
#include <hip/hip_runtime.h>
#include <hip/hip_bf16.h>

using bf16x8 = __attribute__((ext_vector_type(8))) short;
using f32x4  = __attribute__((ext_vector_type(4))) float;

constexpr int CH  = 64;
constexpr int HW  = 11;
constexpr int NP  = 121;
constexpr int PPW = 14;            // padded pos-grid row width
constexpr int NROW = 182;          // padded rows (13*14)
constexpr int ICL = 72;            // ic stride (ush) in img/LDS (bank-safe)
constexpr int IMG_USH = NROW * ICL;        // 13104 ush live data
constexpr int IMG_I4  = IMG_USH / 8;       // 1638 int4
constexpr int IMG_P   = 13312;             // padded stride: 26 x 1024B segments
constexpr int NSEG    = 26;
constexpr int NO  = 7168;          // padded o rows (112 oc * 64 ic)
constexpr float EPS = 1e-5f;

__device__ __forceinline__ f32x4 MFMA(bf16x8 a, bf16x8 b, f32x4 c) {
    return __builtin_amdgcn_mfma_f32_16x16x32_bf16(a, b, c, 0, 0, 0);
}

// ---- prep: bake BN-scaled gw into gen-MFMA A-fragment order + beta ----
__global__ __launch_bounds__(256) void prep_kernel(
    const float* __restrict__ gw, const float* __restrict__ gb,
    const float* __restrict__ bng, const float* __restrict__ bnb,
    const float* __restrict__ bnm, const float* __restrict__ bnv,
    unsigned short* __restrict__ Aprep, float* __restrict__ Beta)
{
    int o = blockIdx.x * 256 + threadIdx.x;
    if (o >= NO) return;
    float inv = 0.f, beta = 0.f;
    if (o < 6400) {
        inv  = bng[o] * rsqrtf(bnv[o] + EPS);
        beta = (gb[o] - bnm[o]) * inv + bnb[o];
    }
    Beta[o] = beta;
    int tile = o >> 4, lrow = o & 15;
    #pragma unroll
    for (int jg = 0; jg < 4; ++jg) {
        bf16x8 f;
        #pragma unroll
        for (int r = 0; r < 8; ++r) {
            int k = jg * 8 + r;
            float v = (o < 6400 && k < 18) ? gw[(size_t)o * 18 + k] * inv : 0.f;
            __hip_bfloat16 h = __float2bfloat16(v);
            f[r] = *(short*)&h;
        }
        ((bf16x8*)Aprep)[tile * 64 + jg * 16 + lrow] = f;
    }
}

// ---- pool: coalesced load -> LDS(72-stride) -> stats + linear img dump ----
__global__ __launch_bounds__(256) void pool_kernel(
    const float* __restrict__ x_in,
    unsigned short* __restrict__ img,   // [1024][IMG_P], 72-ush rows
    unsigned short* __restrict__ Bg)    // [1024][512]
{
    __shared__ alignas(16) unsigned short xsT[IMG_USH];  // 26208 B
    __shared__ float xh[2][128];
    __shared__ float xhp[2][2][128];

    const int phys = blockIdx.x;
    const int b = (phys & 7) * 128 + (phys >> 3);   // XCD-chunked
    const int t = threadIdx.x, lane = t & 63, wave = t >> 6;
    const float* xb = x_in + (size_t)b * (CH * NP);
    unsigned short* ib = img + (size_t)b * IMG_P;

    for (int i = t; i < IMG_USH / 2; i += 256) ((unsigned int*)xsT)[i] = 0u;
    __syncthreads();

    {   // coalesced fp32 loads (lane->pos), bf16 scatter (2-way banks max)
        int p = (wave & 1) * 64 + lane, ich = wave >> 1;
        if (p < NP) {
            int pp = (p / HW + 1) * PPW + (p % HW + 1);
            float s = 0.f, m = -INFINITY;
            const float* xc = xb + (ich * 32) * NP + p;
            #pragma unroll 8
            for (int q = 0; q < 32; ++q) {
                float v = xc[q * NP];
                s += v; m = fmaxf(m, v);
                __hip_bfloat16 h = __float2bfloat16(v);
                xsT[pp * ICL + ich * 32 + q] = *(unsigned short*)&h;
            }
            xhp[ich][0][p] = s;
            xhp[ich][1][p] = m;
        }
    }
    __syncthreads();
    if (t < NP) {
        xh[0][t] = (xhp[0][0][t] + xhp[1][0][t]) * (1.f / 64.f);
        xh[1][t] = fmaxf(xhp[0][1][t], xhp[1][1][t]);
    }
    __syncthreads();

    // Bg[tap(16)][k(32)] zero-padded gen-B matrix
    for (int i = t; i < 512; i += 256) {
        int tap = i >> 5, k = i & 31;
        float val = 0.f;
        if (tap < 9 && k < 18) {
            int ci = k / 9, o9 = k - ci * 9, u = o9 / 3, v = o9 - u * 3;
            int kh = tap / 3, kw = tap - kh * 3;
            val = xh[ci][(4 * kh + u) * HW + (4 * kw + v)];
        }
        __hip_bfloat16 h = __float2bfloat16(val);
        Bg[b * 512 + i] = *(unsigned short*)&h;
    }

    // linear dump LDS -> img (16B reads conflict-free, 16B coalesced stores)
    for (int i = t; i < IMG_I4; i += 256)
        ((int4*)ib)[i] = ((const int4*)xsT)[i];
}

// ---- main: 512 thr = (sample, 2x14-oc chunks); async img staging; 1 barrier ----
__global__ __launch_bounds__(512, 4) void hsi_main(
    const unsigned short* __restrict__ img,
    const unsigned short* __restrict__ Bg,
    const unsigned short* __restrict__ Aprep,
    const float* __restrict__ Beta,
    float* __restrict__ out)
{
    __shared__ alignas(16) unsigned short xs[IMG_P];             // 26624 B
    __shared__ alignas(16) unsigned short strip[2][18 * 64 * 8]; // 36864 B
    // total 63488 B -> 2 blocks/CU (16 waves)

    const int phys = blockIdx.x;
    const int L = (phys & 7) * 512 + (phys >> 3);   // XCD-chunked bijection
    const int b = L >> 2, d = L & 3;                // sample, chunk-pair
    const int t = threadIdx.x;
    const int lane = t & 63, wave = t >> 6;
    const int lrow = lane & 15, jg = lane >> 4;
    const int cl = wave >> 2;                       // strip/chunk select (0/1)
    const int chunk = d * 2 + cl;                   // 14-oc chunk (0..7)

    // 1) async stage img -> xs: global_load_lds width=16, wave-uniform dest
    {
        const unsigned short* ib = img + (size_t)b * IMG_P;
        #pragma unroll
        for (int i = 0; i < 4; ++i) {
            int seg = wave + i * 8;                 // wave-uniform
            if (seg < NSEG)
                __builtin_amdgcn_global_load_lds(
                    (const __attribute__((address_space(1))) void*)(ib + seg * 512 + lane * 8),
                    (__attribute__((address_space(3))) void*)(xs + seg * 512),
                    16, 0, 0);
        }
    }

    // 2) gen-B fragment
    const bf16x8 Bgen = *(const bf16x8*)(Bg + b * 512 + lrow * 32 + jg * 8);

    // 3) gen: 14 MFMAs/wave -> fragment-slot strip (R8-validated layout)
    unsigned short* sp = strip[cl];
    #pragma unroll 2
    for (int it = 0; it < 14; ++it) {
        int tl = (wave & 3) * 14 + it;    // chunk-local gen tile (0..55)
        int tG = chunk * 56 + tl;         // global gen tile (<448)
        bf16x8 A = *(const bf16x8*)(Aprep + ((size_t)tG * 64 + lane) * 8);
        f32x4 acc{};
        acc = MFMA(A, Bgen, acc);
        float4 bet = *(const float4*)(Beta + tG * 16 + jg * 4);
        if (lrow < 9) {                   // C col = tap = lrow; rows = 4 ics
            float v0 = fmaxf(acc[0] + bet.x, 0.f);
            float v1 = fmaxf(acc[1] + bet.y, 0.f);
            float v2 = fmaxf(acc[2] + bet.z, 0.f);
            float v3 = fmaxf(acc[3] + bet.w, 0.f);
            __hip_bfloat16 h0 = __float2bfloat16(v0), h1 = __float2bfloat16(v1);
            __hip_bfloat16 h2 = __float2bfloat16(v2), h3 = __float2bfloat16(v3);
            unsigned int lo = (unsigned int)*(unsigned short*)&h0 |
                              ((unsigned int)*(unsigned short*)&h1 << 16);
            unsigned int hi = (unsigned int)*(unsigned short*)&h2 |
                              ((unsigned int)*(unsigned short*)&h3 << 16);
            // value = W[oc_l][ic = icb*16 + jg*4 + q][tap=lrow]
            int oc_l = tl >> 2, icb = tl & 3;
            int h   = icb >> 1;                    // k-half
            int jgr = (icb & 1) * 2 + (jg >> 1);   // reader k-group
            int slot = (jgr * 16 + oc_l) ^ lrow;
            uint2 pk; pk.x = lo; pk.y = hi;
            *(uint2*)(sp + ((lrow * 2 + h) * 64 + slot) * 8 + (jg & 1) * 4) = pk;
        }
    }

    __syncthreads();   // drains vmcnt (async loads) + lgkmcnt; the only barrier

    // 4) main GEMM: wave = (chunk cl, N-tile pair wave&3); A slot-read, B from LDS
    int p0 = (wave & 3) * 32 + lrow;
    int p1 = p0 + 16;
    int pc0 = p0 > 120 ? 120 : p0;
    int pc1 = p1 > 120 ? 120 : p1;
    int base0 = (pc0 / HW) * PPW + (pc0 % HW);
    int base1 = (pc1 / HW) * PPW + (pc1 % HW);

    f32x4 acc0{}, acc1{};
    #pragma unroll
    for (int tap = 0; tap < 9; ++tap) {
        int off = (tap / 3) * PPW + (tap % 3);
        int r0 = (base0 + off) * ICL;
        int r1 = (base1 + off) * ICL;
        #pragma unroll
        for (int h = 0; h < 2; ++h) {
            bf16x8 Af = *(const bf16x8*)&sp[((tap * 2 + h) * 64 + (lane ^ tap)) * 8];
            bf16x8 B0 = *(const bf16x8*)&xs[r0 + h * 32 + jg * 8];
            bf16x8 B1 = *(const bf16x8*)&xs[r1 + h * 32 + jg * 8];
            acc0 = MFMA(Af, B0, acc0);
            acc1 = MFMA(Af, B1, acc1);
        }
    }

    float* ob = out + (size_t)b * 100 * NP;
    #pragma unroll
    for (int ri = 0; ri < 4; ++ri) {
        int row = jg * 4 + ri;            // oc-local; rows 14,15 = next chunk
        int oc = chunk * 14 + row;
        if (row < 14 && oc < 100) {
            if (p0 < NP) ob[oc * NP + p0] = acc0[ri];
            if (p1 < NP) ob[oc * NP + p1] = acc1[ri];
        }
    }
}

extern "C" void kernel_launch(void* const* d_in, const int* in_sizes, int n_in,
                              void* d_out, int out_size, void* d_ws, size_t ws_size,
                              hipStream_t stream) {
    const float* x  = (const float*)d_in[0];
    const float* gw = (const float*)d_in[1];
    const float* gb = (const float*)d_in[2];
    const float* bg = (const float*)d_in[3];
    const float* bb = (const float*)d_in[4];
    const float* bm = (const float*)d_in[5];
    const float* bv = (const float*)d_in[6];
    float* out = (float*)d_out;

    // ws: Aprep 458752 | Beta 28672 | Bg 1048576 | img 1024*26624  (~28.8 MiB)
    unsigned short* Aprep = (unsigned short*)d_ws;
    float* Beta = (float*)((char*)d_ws + 458752);
    unsigned short* Bgm = (unsigned short*)((char*)d_ws + 487424);
    unsigned short* img = (unsigned short*)((char*)d_ws + 1536000);

    prep_kernel<<<NO / 256, 256, 0, stream>>>(gw, gb, bg, bb, bm, bv, Aprep, Beta);
    pool_kernel<<<1024, 256, 0, stream>>>(x, img, Bgm);
    hsi_main<<<1024 * 4, 512, 0, stream>>>(img, Bgm, Aprep, Beta, out);
}